// Round 1
// baseline (1637.845 us; speedup 1.0000x reference)
//
#include <hip/hip_runtime.h>

// 2-layer GRU (B=1024, T=512, F=128, H=64) + ReLU + FC(64->18), fp32 in/out.
// Strategy: persistent kernel, 64 blocks x 4 waves. Block owns 16 batch rows
// for the whole T loop. f16 MFMA (16x16x32) with fp32 accumulate; all weight
// B-fragments live in registers; h0/h1 exchanged via LDS (2 barriers/step).
// Wave w owns gate tiles {w, w+4, w+8} = (r,z,n) for h-cols [16w,16w+16) so
// the GRU nonlinearity needs no cross-wave gate exchange.

#define Tn 512
#define Fn 128
#define Hn 64
#define An 18

typedef _Float16 half8 __attribute__((ext_vector_type(8)));
typedef float f32x4 __attribute__((ext_vector_type(4)));

static __device__ __forceinline__ float fast_exp(float x) {
    return __builtin_amdgcn_exp2f(x * 1.4426950408889634f);
}
static __device__ __forceinline__ float sigm(float x) {
    x = fminf(fmaxf(x, -30.f), 30.f);
    return 1.0f / (1.0f + fast_exp(-x));
}
static __device__ __forceinline__ float tanh_f(float x) {
    x = fminf(fmaxf(x, -18.f), 18.f);
    float e = fast_exp(-2.0f * x);
    return (1.0f - e) / (1.0f + e);
}

#define MFMA(a, b, c) __builtin_amdgcn_mfma_f32_16x16x32_f16((a), (b), (c), 0, 0, 0)

__global__ __launch_bounds__(256, 1) void gru_persistent(
    const float* __restrict__ state,
    const float* __restrict__ Wih0, const float* __restrict__ Whh0,
    const float* __restrict__ bih0, const float* __restrict__ bhh0,
    const float* __restrict__ Wih1, const float* __restrict__ Whh1,
    const float* __restrict__ bih1, const float* __restrict__ bhh1,
    const float* __restrict__ fcw, const float* __restrict__ fcb,
    float* __restrict__ out)
{
    const int tid  = threadIdx.x;
    const int wv   = tid >> 6;     // wave id 0..3
    const int lane = tid & 63;
    const int c    = lane & 15;    // col within 16-tile (also A-frag row m)
    const int q    = lane >> 4;    // quad 0..3
    const int r0   = blockIdx.x * 16;

    // h buffers padded to 80 f16/row (160 B) -> conflict-free b128 A-frag reads
    __shared__ __align__(16) _Float16 h0buf[16 * 80];
    __shared__ __align__(16) _Float16 h1buf[16 * 80];
    __shared__ float fbuf[16 * 64];

    // ---- persistent weight B-fragments (B[k][n] = W[n][k], n = gate col) ----
    // gsel: 0 = r gates, 1 = z gates, 2 = n gates. Gate row g = gsel*64 + wv*16 + c.
    half8 Bl0x[3][4], Bl0h[3][2], Bl1x[3][2], Bl1h[3][2];
#pragma unroll
    for (int gsel = 0; gsel < 3; ++gsel) {
        const int g = gsel * 64 + wv * 16 + c;
#pragma unroll
        for (int ks = 0; ks < 4; ++ks) {
            const float* p = Wih0 + g * Fn + ks * 32 + q * 8;
            half8 hb;
#pragma unroll
            for (int j = 0; j < 8; ++j) hb[j] = (_Float16)p[j];
            Bl0x[gsel][ks] = hb;
        }
#pragma unroll
        for (int ks = 0; ks < 2; ++ks) {
            const float* p0 = Whh0 + g * Hn + ks * 32 + q * 8;
            const float* p1 = Wih1 + g * Hn + ks * 32 + q * 8;
            const float* p2 = Whh1 + g * Hn + ks * 32 + q * 8;
            half8 h0b, h1b, h2b;
#pragma unroll
            for (int j = 0; j < 8; ++j) {
                h0b[j] = (_Float16)p0[j];
                h1b[j] = (_Float16)p1[j];
                h2b[j] = (_Float16)p2[j];
            }
            Bl0h[gsel][ks] = h0b;
            Bl1x[gsel][ks] = h1b;
            Bl1h[gsel][ks] = h2b;
        }
    }

    // biases (depend only on the lane's gate column)
    const int gc = wv * 16 + c;
    const float br0  = bih0[gc]       + bhh0[gc];
    const float bz0  = bih0[64 + gc]  + bhh0[64 + gc];
    const float bxn0 = bih0[128 + gc];
    const float bhn0 = bhh0[128 + gc];
    const float br1  = bih1[gc]       + bhh1[gc];
    const float bz1  = bih1[64 + gc]  + bhh1[64 + gc];
    const float bxn1 = bih1[128 + gc];
    const float bhn1 = bhh1[128 + gc];

    // ---- state: hidden kept in fp32 C-layout regs; f16 copies via LDS ----
    f32x4 h0reg = {0.f, 0.f, 0.f, 0.f};
    f32x4 h1reg = {0.f, 0.f, 0.f, 0.f};
    half8 h0frag[2], h1frag[2];
#pragma unroll
    for (int ks = 0; ks < 2; ++ks)
#pragma unroll
        for (int j = 0; j < 8; ++j) { h0frag[ks][j] = (_Float16)0.f; h1frag[ks][j] = (_Float16)0.f; }

    // x prefetch registers: 8 consecutive f32 per lane per k-step (A-frag source)
    const float* srow = state + (size_t)(r0 + c) * (Tn * Fn);
    f32x4 xp[8];
#pragma unroll
    for (int ks = 0; ks < 4; ++ks) {
        const float* p = srow + ks * 32 + q * 8;
        xp[2 * ks]     = *(const f32x4*)(p);
        xp[2 * ks + 1] = *(const f32x4*)(p + 4);
    }

    for (int t = 0; t < Tn; ++t) {
        // convert prefetched x_t to f16 A-frags
        half8 xfrag[4];
#pragma unroll
        for (int ks = 0; ks < 4; ++ks) {
#pragma unroll
            for (int j = 0; j < 4; ++j) {
                xfrag[ks][j]     = (_Float16)xp[2 * ks][j];
                xfrag[ks][4 + j] = (_Float16)xp[2 * ks + 1][j];
            }
        }
        // issue prefetch for t+1 (in flight during this step's compute)
        const int tn = (t + 1 < Tn) ? (t + 1) : t;
#pragma unroll
        for (int ks = 0; ks < 4; ++ks) {
            const float* p = srow + tn * Fn + ks * 32 + q * 8;
            xp[2 * ks]     = *(const f32x4*)(p);
            xp[2 * ks + 1] = *(const f32x4*)(p + 4);
        }

        // ---------------- layer 0 ----------------
        f32x4 accr  = {br0, br0, br0, br0};
        f32x4 accz  = {bz0, bz0, bz0, bz0};
        f32x4 accxn = {bxn0, bxn0, bxn0, bxn0};
        f32x4 acchn = {bhn0, bhn0, bhn0, bhn0};
#pragma unroll
        for (int ks = 0; ks < 4; ++ks) {
            accr  = MFMA(xfrag[ks], Bl0x[0][ks], accr);
            accz  = MFMA(xfrag[ks], Bl0x[1][ks], accz);
            accxn = MFMA(xfrag[ks], Bl0x[2][ks], accxn);
        }
#pragma unroll
        for (int ks = 0; ks < 2; ++ks) {
            accr  = MFMA(h0frag[ks], Bl0h[0][ks], accr);
            accz  = MFMA(h0frag[ks], Bl0h[1][ks], accz);
            acchn = MFMA(h0frag[ks], Bl0h[2][ks], acchn);
        }
        f32x4 h0new;
#pragma unroll
        for (int i = 0; i < 4; ++i) {
            float rg = sigm(accr[i]);
            float zg = sigm(accz[i]);
            float ng = tanh_f(accxn[i] + rg * acchn[i]);
            h0new[i] = ng + zg * (h0reg[i] - ng);
        }
        h0reg = h0new;
#pragma unroll
        for (int i = 0; i < 4; ++i)
            h0buf[(q * 4 + i) * 80 + wv * 16 + c] = (_Float16)h0new[i];
        __syncthreads();
#pragma unroll
        for (int ks = 0; ks < 2; ++ks)
            h0frag[ks] = *(const half8*)&h0buf[c * 80 + ks * 32 + q * 8];

        // ---------------- layer 1 ----------------
        accr  = (f32x4){br1, br1, br1, br1};
        accz  = (f32x4){bz1, bz1, bz1, bz1};
        accxn = (f32x4){bxn1, bxn1, bxn1, bxn1};
        acchn = (f32x4){bhn1, bhn1, bhn1, bhn1};
#pragma unroll
        for (int ks = 0; ks < 2; ++ks) {
            accr  = MFMA(h0frag[ks], Bl1x[0][ks], accr);
            accz  = MFMA(h0frag[ks], Bl1x[1][ks], accz);
            accxn = MFMA(h0frag[ks], Bl1x[2][ks], accxn);
            accr  = MFMA(h1frag[ks], Bl1h[0][ks], accr);
            accz  = MFMA(h1frag[ks], Bl1h[1][ks], accz);
            acchn = MFMA(h1frag[ks], Bl1h[2][ks], acchn);
        }
        f32x4 h1new;
#pragma unroll
        for (int i = 0; i < 4; ++i) {
            float rg = sigm(accr[i]);
            float zg = sigm(accz[i]);
            float ng = tanh_f(accxn[i] + rg * acchn[i]);
            h1new[i] = ng + zg * (h1reg[i] - ng);
        }
        h1reg = h1new;
#pragma unroll
        for (int i = 0; i < 4; ++i)
            h1buf[(q * 4 + i) * 80 + wv * 16 + c] = (_Float16)h1new[i];
        __syncthreads();
#pragma unroll
        for (int ks = 0; ks < 2; ++ks)
            h1frag[ks] = *(const half8*)&h1buf[c * 80 + ks * 32 + q * 8];
    }

    // ---------------- epilogue: relu(h1) @ fc3_w.T + fc3_b ----------------
#pragma unroll
    for (int i = 0; i < 4; ++i)
        fbuf[(q * 4 + i) * 64 + wv * 16 + c] = fmaxf(h1reg[i], 0.0f);
    __syncthreads();
    for (int idx = tid; idx < 16 * An; idx += 256) {
        const int row = idx / An;
        const int a   = idx - row * An;
        float acc = fcb[a];
#pragma unroll 16
        for (int k = 0; k < Hn; ++k)
            acc += fbuf[row * 64 + k] * fcw[a * 64 + k];
        out[(size_t)(r0 + row) * An + a] = acc;
    }
}

extern "C" void kernel_launch(void* const* d_in, const int* in_sizes, int n_in,
                              void* d_out, int out_size, void* d_ws, size_t ws_size,
                              hipStream_t stream) {
    const float* state = (const float*)d_in[0];
    const float* Wih0  = (const float*)d_in[1];
    const float* Whh0  = (const float*)d_in[2];
    const float* bih0  = (const float*)d_in[3];
    const float* bhh0  = (const float*)d_in[4];
    const float* Wih1  = (const float*)d_in[5];
    const float* Whh1  = (const float*)d_in[6];
    const float* bih1  = (const float*)d_in[7];
    const float* bhh1  = (const float*)d_in[8];
    const float* fcw   = (const float*)d_in[9];
    const float* fcb   = (const float*)d_in[10];
    float* out = (float*)d_out;

    gru_persistent<<<64, 256, 0, stream>>>(state, Wih0, Whh0, bih0, bhh0,
                                           Wih1, Whh1, bih1, bhh1, fcw, fcb, out);
}

// Round 2
// 816.754 us; speedup vs baseline: 2.0053x; 2.0053x over previous
//
#include <hip/hip_runtime.h>

// 2-layer GRU (B=1024, T=512, F=128, H=64) + ReLU + FC(64->18), fp32 in/out.
//
// R2 structure:
//  Kernel 1 (gx_pregemm, 4096 blocks): gx[t] = x[t] @ W_ih0.T + (bih0 + bhh0[r,z])
//    precomputed for ALL timesteps (time-parallel), stored f16 in d_ws in the
//    exact per-lane C-layout the recurrent kernel consumes (3 x b64 loads/step).
//  Kernel 2 (gru_rec, 64 blocks x 8 waves): waves 0-3 = layer0 chain, waves
//    4-7 = layer1 chain lagged one step (h0(t) -> layer0(t+1) || layer1(t)).
//    One barrier per tick; h0/h1 exchanged via double-buffered LDS.
//  Fallback (ws too small): gru_rec<false> does the layer0 x-matvec in-loop.

#define Tn 512
#define Fn 128
#define Hn 64
#define An 18
#define TS 8
// gx layout: [t][tile(64)][wv(4)][gsel(3)][lane(64)][4]  (_Float16)
#define GX_T_ELEMS (64 * 4 * 3 * 64 * 4)   // 196608 elements per timestep
#define GX_BYTES ((size_t)Tn * GX_T_ELEMS * 2)

typedef _Float16 half8 __attribute__((ext_vector_type(8)));
typedef _Float16 half4 __attribute__((ext_vector_type(4)));
typedef float f32x4 __attribute__((ext_vector_type(4)));

#define MFMA(a, b, c) __builtin_amdgcn_mfma_f32_16x16x32_f16((a), (b), (c), 0, 0, 0)

// Clamp-free: exp2(+inf)->inf, rcp(inf)->0, so both saturate correctly.
static __device__ __forceinline__ float sigm(float x) {
    return __builtin_amdgcn_rcpf(1.0f + __builtin_amdgcn_exp2f(-1.4426950408889634f * x));
}
static __device__ __forceinline__ float tanh_f(float x) {
    return 2.0f * __builtin_amdgcn_rcpf(1.0f + __builtin_amdgcn_exp2f(-2.8853900817779268f * x)) - 1.0f;
}

__global__ __launch_bounds__(256, 1) void gx_pregemm(
    const float* __restrict__ state, const float* __restrict__ Wih0,
    const float* __restrict__ bih0, const float* __restrict__ bhh0,
    _Float16* __restrict__ gx)
{
    const int tid = threadIdx.x;
    const int wv = tid >> 6, lane = tid & 63;
    const int c = lane & 15, q = lane >> 4;
    const int tile = blockIdx.x;
    const int t0 = blockIdx.y * TS;

    half8 Bx[3][4];
    f32x4 binit[3];
#pragma unroll
    for (int gsel = 0; gsel < 3; ++gsel) {
        const int g = gsel * 64 + wv * 16 + c;
        const float b = bih0[g] + (gsel < 2 ? bhh0[g] : 0.0f);
        binit[gsel] = (f32x4){b, b, b, b};
#pragma unroll
        for (int ks = 0; ks < 4; ++ks) {
            const float* p = Wih0 + g * Fn + ks * 32 + q * 8;
#pragma unroll
            for (int j = 0; j < 8; ++j) Bx[gsel][ks][j] = (_Float16)p[j];
        }
    }
    const float* srow = state + (size_t)(tile * 16 + c) * (Tn * Fn) + (size_t)t0 * Fn;
    _Float16* gp = gx + (size_t)t0 * GX_T_ELEMS + tile * 3072 + wv * 768 + lane * 4;

    for (int j = 0; j < TS; ++j) {
        half8 xf[4];
#pragma unroll
        for (int ks = 0; ks < 4; ++ks) {
            f32x4 a  = *(const f32x4*)(srow + (size_t)j * Fn + ks * 32 + q * 8);
            f32x4 b2 = *(const f32x4*)(srow + (size_t)j * Fn + ks * 32 + q * 8 + 4);
#pragma unroll
            for (int i = 0; i < 4; ++i) { xf[ks][i] = (_Float16)a[i]; xf[ks][4 + i] = (_Float16)b2[i]; }
        }
        f32x4 a0 = binit[0], a1 = binit[1], a2 = binit[2];
#pragma unroll
        for (int ks = 0; ks < 4; ++ks) {
            a0 = MFMA(xf[ks], Bx[0][ks], a0);
            a1 = MFMA(xf[ks], Bx[1][ks], a1);
            a2 = MFMA(xf[ks], Bx[2][ks], a2);
        }
        half4 o0, o1, o2;
#pragma unroll
        for (int i = 0; i < 4; ++i) {
            o0[i] = (_Float16)a0[i]; o1[i] = (_Float16)a1[i]; o2[i] = (_Float16)a2[i];
        }
        *(half4*)(gp + (size_t)j * GX_T_ELEMS)       = o0;
        *(half4*)(gp + (size_t)j * GX_T_ELEMS + 256) = o1;
        *(half4*)(gp + (size_t)j * GX_T_ELEMS + 512) = o2;
    }
}

template <bool PRE>
__global__ __launch_bounds__(512, 1) void gru_rec(
    const float* __restrict__ state, const _Float16* __restrict__ gx,
    const float* __restrict__ Wih0, const float* __restrict__ Whh0,
    const float* __restrict__ bih0, const float* __restrict__ bhh0,
    const float* __restrict__ Wih1, const float* __restrict__ Whh1,
    const float* __restrict__ bih1, const float* __restrict__ bhh1,
    const float* __restrict__ fcw, const float* __restrict__ fcb,
    float* __restrict__ out)
{
    const int tid = threadIdx.x;
    const int wv8 = tid >> 6;
    const int lane = tid & 63, c = lane & 15, q = lane >> 4;
    const bool isL0 = (wv8 < 4);
    const int wv = wv8 & 3;
    const int tile = blockIdx.x, r0 = tile * 16;
    const int gc = wv * 16 + c;

    __shared__ __align__(16) _Float16 h0buf[2][16 * 80];
    __shared__ __align__(16) _Float16 h1buf[2][16 * 80];
    __shared__ float fbuf[16 * 64];

    for (int i = tid; i < 2 * 16 * 80; i += 512) {
        (&h0buf[0][0])[i] = (_Float16)0.0f;
        (&h1buf[0][0])[i] = (_Float16)0.0f;
    }

    // BA: k = previous-layer input (L0: Whh0 on h0; L1: Wih1 on h0)
    // BB: k = own hidden (L1: Whh1 on h1)
    half8 BA[3][2], BB[3][2], BX[3][4];
    f32x4 bias_r, bias_z, bias_xn, bias_hn;
    if (isL0) {
#pragma unroll
        for (int gsel = 0; gsel < 3; ++gsel) {
            const int g = gsel * 64 + gc;
#pragma unroll
            for (int ks = 0; ks < 2; ++ks) {
                const float* p = Whh0 + g * Hn + ks * 32 + q * 8;
#pragma unroll
                for (int j = 0; j < 8; ++j) BA[gsel][ks][j] = (_Float16)p[j];
            }
            if (!PRE) {
#pragma unroll
                for (int ks = 0; ks < 4; ++ks) {
                    const float* p = Wih0 + g * Fn + ks * 32 + q * 8;
#pragma unroll
                    for (int j = 0; j < 8; ++j) BX[gsel][ks][j] = (_Float16)p[j];
                }
            }
        }
        const float br = bih0[gc] + bhh0[gc];
        const float bz = bih0[64 + gc] + bhh0[64 + gc];
        const float bxn = bih0[128 + gc];
        const float bhn = bhh0[128 + gc];
        bias_r  = (f32x4){br, br, br, br};
        bias_z  = (f32x4){bz, bz, bz, bz};
        bias_xn = (f32x4){bxn, bxn, bxn, bxn};
        bias_hn = (f32x4){bhn, bhn, bhn, bhn};
    } else {
#pragma unroll
        for (int gsel = 0; gsel < 3; ++gsel) {
            const int g = gsel * 64 + gc;
#pragma unroll
            for (int ks = 0; ks < 2; ++ks) {
                const float* pa = Wih1 + g * Hn + ks * 32 + q * 8;
                const float* pb = Whh1 + g * Hn + ks * 32 + q * 8;
#pragma unroll
                for (int j = 0; j < 8; ++j) {
                    BA[gsel][ks][j] = (_Float16)pa[j];
                    BB[gsel][ks][j] = (_Float16)pb[j];
                }
            }
        }
        const float br = bih1[gc] + bhh1[gc];
        const float bz = bih1[64 + gc] + bhh1[64 + gc];
        const float bxn = bih1[128 + gc];
        const float bhn = bhh1[128 + gc];
        bias_r  = (f32x4){br, br, br, br};
        bias_z  = (f32x4){bz, bz, bz, bz};
        bias_xn = (f32x4){bxn, bxn, bxn, bxn};
        bias_hn = (f32x4){bhn, bhn, bhn, bhn};
    }

    // layer0 input prefetch
    const _Float16* gp = gx + tile * 3072 + wv * 768 + lane * 4;
    half4 g0p, g1p, g2p;
    const float* srow = state + (size_t)(r0 + c) * (Tn * Fn);
    f32x4 xp[8];
    if (isL0) {
        if (PRE) {
            g0p = *(const half4*)(gp);
            g1p = *(const half4*)(gp + 256);
            g2p = *(const half4*)(gp + 512);
            gp += GX_T_ELEMS;
        } else {
#pragma unroll
            for (int ks = 0; ks < 4; ++ks) {
                xp[2 * ks]     = *(const f32x4*)(srow + ks * 32 + q * 8);
                xp[2 * ks + 1] = *(const f32x4*)(srow + ks * 32 + q * 8 + 4);
            }
        }
    }

    f32x4 hreg = (f32x4){0.f, 0.f, 0.f, 0.f};   // L0: h0; L1: h1 (C-layout)
    const int ardr = c * 80 + q * 8;            // A-frag read base (+ks*32)
    const int wrow = (q * 4) * 80 + gc;         // C-layout write base (+i*80)

    // Tick t: L0 computes h0(t) (t<Tn); L1 computes h1(t-1) (t>=1).
    // Slots: write h0(t)->h0buf[t&1]; write h1(t-1)->h1buf[(t-1)&1].
    for (int t = 0; t <= Tn; ++t) {
        __syncthreads();
        const int pr = (t & 1) ^ 1, pw = (t & 1);
        if (isL0) {
            if (t < Tn) {
                f32x4 accr, accz, accxn, acchn;
                if (PRE) {
#pragma unroll
                    for (int i = 0; i < 4; ++i) {
                        accr[i]  = (float)g0p[i];
                        accz[i]  = (float)g1p[i];
                        accxn[i] = (float)g2p[i];
                    }
                    if (t + 1 < Tn) {
                        g0p = *(const half4*)(gp);
                        g1p = *(const half4*)(gp + 256);
                        g2p = *(const half4*)(gp + 512);
                        gp += GX_T_ELEMS;
                    }
                } else {
                    half8 xf[4];
#pragma unroll
                    for (int ks = 0; ks < 4; ++ks) {
#pragma unroll
                        for (int i = 0; i < 4; ++i) {
                            xf[ks][i]     = (_Float16)xp[2 * ks][i];
                            xf[ks][4 + i] = (_Float16)xp[2 * ks + 1][i];
                        }
                    }
                    const int tnx = (t + 1 < Tn) ? (t + 1) : t;
#pragma unroll
                    for (int ks = 0; ks < 4; ++ks) {
                        xp[2 * ks]     = *(const f32x4*)(srow + (size_t)tnx * Fn + ks * 32 + q * 8);
                        xp[2 * ks + 1] = *(const f32x4*)(srow + (size_t)tnx * Fn + ks * 32 + q * 8 + 4);
                    }
                    accr = bias_r; accz = bias_z; accxn = bias_xn;
#pragma unroll
                    for (int ks = 0; ks < 4; ++ks) {
                        accr  = MFMA(xf[ks], BX[0][ks], accr);
                        accz  = MFMA(xf[ks], BX[1][ks], accz);
                        accxn = MFMA(xf[ks], BX[2][ks], accxn);
                    }
                }
                const half8 hf0 = *(const half8*)&h0buf[pr][ardr];
                const half8 hf1 = *(const half8*)&h0buf[pr][ardr + 32];
                accr  = MFMA(hf0, BA[0][0], accr);
                accr  = MFMA(hf1, BA[0][1], accr);
                accz  = MFMA(hf0, BA[1][0], accz);
                accz  = MFMA(hf1, BA[1][1], accz);
                acchn = MFMA(hf0, BA[2][0], bias_hn);
                acchn = MFMA(hf1, BA[2][1], acchn);
#pragma unroll
                for (int i = 0; i < 4; ++i) {
                    const float rg = sigm(accr[i]);
                    const float zg = sigm(accz[i]);
                    const float ng = tanh_f(accxn[i] + rg * acchn[i]);
                    hreg[i] = ng + zg * (hreg[i] - ng);
                }
#pragma unroll
                for (int i = 0; i < 4; ++i) h0buf[pw][wrow + i * 80] = (_Float16)hreg[i];
            }
        } else {
            if (t >= 1) {
                const half8 xf0 = *(const half8*)&h0buf[pr][ardr];
                const half8 xf1 = *(const half8*)&h0buf[pr][ardr + 32];
                const half8 hf0 = *(const half8*)&h1buf[pw][ardr];
                const half8 hf1 = *(const half8*)&h1buf[pw][ardr + 32];
                f32x4 accr = bias_r, accz = bias_z, accxn = bias_xn, acchn;
                accr  = MFMA(xf0, BA[0][0], accr);
                accr  = MFMA(xf1, BA[0][1], accr);
                accz  = MFMA(xf0, BA[1][0], accz);
                accz  = MFMA(xf1, BA[1][1], accz);
                accxn = MFMA(xf0, BA[2][0], accxn);
                accxn = MFMA(xf1, BA[2][1], accxn);
                accr  = MFMA(hf0, BB[0][0], accr);
                accr  = MFMA(hf1, BB[0][1], accr);
                accz  = MFMA(hf0, BB[1][0], accz);
                accz  = MFMA(hf1, BB[1][1], accz);
                acchn = MFMA(hf0, BB[2][0], bias_hn);
                acchn = MFMA(hf1, BB[2][1], acchn);
#pragma unroll
                for (int i = 0; i < 4; ++i) {
                    const float rg = sigm(accr[i]);
                    const float zg = sigm(accz[i]);
                    const float ng = tanh_f(accxn[i] + rg * acchn[i]);
                    hreg[i] = ng + zg * (hreg[i] - ng);
                }
#pragma unroll
                for (int i = 0; i < 4; ++i) h1buf[pr][wrow + i * 80] = (_Float16)hreg[i];
            }
        }
    }

    // epilogue: relu(h1_final) @ fc3_w.T + fc3_b
    if (!isL0) {
#pragma unroll
        for (int i = 0; i < 4; ++i) fbuf[(q * 4 + i) * 64 + gc] = fmaxf(hreg[i], 0.0f);
    }
    __syncthreads();
    for (int idx = tid; idx < 16 * An; idx += 512) {
        const int row = idx / An, a = idx - row * An;
        float acc = fcb[a];
#pragma unroll 16
        for (int k = 0; k < Hn; ++k) acc += fbuf[row * 64 + k] * fcw[a * Hn + k];
        out[(size_t)(r0 + row) * An + a] = acc;
    }
}

extern "C" void kernel_launch(void* const* d_in, const int* in_sizes, int n_in,
                              void* d_out, int out_size, void* d_ws, size_t ws_size,
                              hipStream_t stream) {
    const float* state = (const float*)d_in[0];
    const float* Wih0  = (const float*)d_in[1];
    const float* Whh0  = (const float*)d_in[2];
    const float* bih0  = (const float*)d_in[3];
    const float* bhh0  = (const float*)d_in[4];
    const float* Wih1  = (const float*)d_in[5];
    const float* Whh1  = (const float*)d_in[6];
    const float* bih1  = (const float*)d_in[7];
    const float* bhh1  = (const float*)d_in[8];
    const float* fcw   = (const float*)d_in[9];
    const float* fcb   = (const float*)d_in[10];
    float* out = (float*)d_out;

    if (ws_size >= GX_BYTES) {
        _Float16* gx = (_Float16*)d_ws;
        gx_pregemm<<<dim3(64, Tn / TS), 256, 0, stream>>>(state, Wih0, bih0, bhh0, gx);
        gru_rec<true><<<64, 512, 0, stream>>>(state, gx, Wih0, Whh0, bih0, bhh0,
                                              Wih1, Whh1, bih1, bhh1, fcw, fcb, out);
    } else {
        gru_rec<false><<<64, 512, 0, stream>>>(state, (const _Float16*)d_ws,
                                               Wih0, Whh0, bih0, bhh0,
                                               Wih1, Whh1, bih1, bhh1, fcw, fcb, out);
    }
}

// Round 3
// 741.915 us; speedup vs baseline: 2.2076x; 1.1009x over previous
//
#include <hip/hip_runtime.h>

// 2-layer GRU (B=1024, T=512, F=128, H=64) + ReLU + FC(64->18), fp32 in/out.
//
// R3: single fused persistent kernel. 64 blocks x 768 threads (12 waves,
// 3 per SIMD), one block per 16-row batch tile:
//   waves 0-3  (P):  gx(t+1) = x(t+1) @ W_ih0.T + bias, 12 MFMAs, written to
//                    a 2-slot LDS ring in f32 C-layout (no f16 round-trip).
//                    Distance-1 HBM prefetch of x; P has ~600cyc slack/tick.
//   waves 4-7  (L0): h0(t) = GRUcell(gx(t), h0(t-1))   [6 MFMA + nonlin]
//   waves 8-11 (L1): h1(t-1) = GRUcell(h0(t-1), h1(t-2)) [12 MFMA + nonlin]
// One __syncthreads per tick. Weight fragments unioned in W[12] to keep
// VGPR <= ~150 so 12 waves/CU are resident (limit 170 at 3 waves/SIMD).

#define Tn 512
#define Fn 128
#define Hn 64
#define An 18
// padded h row stride (halves): 72 -> 144B rows, start-bank gcd 4 -> 2-way (free)
#define HS 72

typedef _Float16 half8 __attribute__((ext_vector_type(8)));
typedef float f32x4 __attribute__((ext_vector_type(4)));

#define MFMA(a, b, c) __builtin_amdgcn_mfma_f32_16x16x32_f16((a), (b), (c), 0, 0, 0)

// Clamp-free: exp2(+-inf) saturates, rcp(inf)->0.
static __device__ __forceinline__ float sigm(float x) {
    return __builtin_amdgcn_rcpf(1.0f + __builtin_amdgcn_exp2f(-1.4426950408889634f * x));
}
static __device__ __forceinline__ float tanh_f(float x) {
    return 2.0f * __builtin_amdgcn_rcpf(1.0f + __builtin_amdgcn_exp2f(-2.8853900817779268f * x)) - 1.0f;
}

__global__ __launch_bounds__(768) void gru_fused(
    const float* __restrict__ state,
    const float* __restrict__ Wih0, const float* __restrict__ Whh0,
    const float* __restrict__ bih0, const float* __restrict__ bhh0,
    const float* __restrict__ Wih1, const float* __restrict__ Whh1,
    const float* __restrict__ bih1, const float* __restrict__ bhh1,
    const float* __restrict__ fcw, const float* __restrict__ fcb,
    float* __restrict__ out)
{
    const int tid  = threadIdx.x;
    const int wv12 = tid >> 6;
    const int lane = tid & 63, c = lane & 15, q = lane >> 4;
    const int wv   = wv12 & 3;
    const int r0   = blockIdx.x * 16;
    const int gc   = wv * 16 + c;
    const int role = (wv12 < 4) ? 0 : (wv12 < 8 ? 1 : 2);

    __shared__ __align__(16) float    gxring[2][4][3][64][4];   // 24 KiB
    __shared__ __align__(16) _Float16 h0buf[2][16 * HS];        // 4.5 KiB
    __shared__ __align__(16) _Float16 h1buf[2][16 * HS];        // 4.5 KiB
    __shared__ float fbuf[16 * 64];                             // 4 KiB

    for (int i = tid; i < 2 * 16 * HS; i += 768) {
        (&h0buf[0][0])[i] = (_Float16)0.0f;
        (&h1buf[0][0])[i] = (_Float16)0.0f;
    }

    // Unioned weight fragments:
    //  P : W[gsel*4+ks] = Wih0 (k=128, 4 ksteps)
    //  L0: W[gsel*2+ks] = Whh0 (k=64, 2 ksteps)
    //  L1: W[gsel*2+ks] = Wih1 ; W[6+gsel*2+ks] = Whh1
    half8 W[12];
    f32x4 bias0, bias1, bias2, bias3;
    f32x4 xf32[8];
    f32x4 hreg = {0.f, 0.f, 0.f, 0.f};
    const float* srow = state + (size_t)(r0 + c) * (Tn * Fn);

    if (role == 0) {
#pragma unroll
        for (int gsel = 0; gsel < 3; ++gsel) {
            const int g = gsel * 64 + gc;
#pragma unroll
            for (int ks = 0; ks < 4; ++ks) {
                const float* p = Wih0 + g * Fn + ks * 32 + q * 8;
#pragma unroll
                for (int j = 0; j < 8; ++j) W[gsel * 4 + ks][j] = (_Float16)p[j];
            }
        }
        {
            const float b0 = bih0[gc] + bhh0[gc];
            const float b1 = bih0[64 + gc] + bhh0[64 + gc];
            const float b2 = bih0[128 + gc];
            bias0 = (f32x4){b0, b0, b0, b0};
            bias1 = (f32x4){b1, b1, b1, b1};
            bias2 = (f32x4){b2, b2, b2, b2};
        }
        // -------- prologue: gx(0) -> ring slot 0; preload x(1) --------
#pragma unroll
        for (int ks = 0; ks < 4; ++ks) {
            xf32[2 * ks]     = *(const f32x4*)(srow + ks * 32 + q * 8);
            xf32[2 * ks + 1] = *(const f32x4*)(srow + ks * 32 + q * 8 + 4);
        }
        half8 xf[4];
#pragma unroll
        for (int ks = 0; ks < 4; ++ks)
#pragma unroll
            for (int i = 0; i < 4; ++i) {
                xf[ks][i]     = (_Float16)xf32[2 * ks][i];
                xf[ks][4 + i] = (_Float16)xf32[2 * ks + 1][i];
            }
        f32x4 a0 = bias0, a1 = bias1, a2 = bias2;
#pragma unroll
        for (int ks = 0; ks < 4; ++ks) {
            a0 = MFMA(xf[ks], W[ks], a0);
            a1 = MFMA(xf[ks], W[4 + ks], a1);
            a2 = MFMA(xf[ks], W[8 + ks], a2);
        }
        *(f32x4*)&gxring[0][wv][0][lane][0] = a0;
        *(f32x4*)&gxring[0][wv][1][lane][0] = a1;
        *(f32x4*)&gxring[0][wv][2][lane][0] = a2;
#pragma unroll
        for (int ks = 0; ks < 4; ++ks) {
            xf32[2 * ks]     = *(const f32x4*)(srow + Fn + ks * 32 + q * 8);
            xf32[2 * ks + 1] = *(const f32x4*)(srow + Fn + ks * 32 + q * 8 + 4);
        }
    } else if (role == 1) {
#pragma unroll
        for (int gsel = 0; gsel < 3; ++gsel) {
            const int g = gsel * 64 + gc;
#pragma unroll
            for (int ks = 0; ks < 2; ++ks) {
                const float* p = Whh0 + g * Hn + ks * 32 + q * 8;
#pragma unroll
                for (int j = 0; j < 8; ++j) W[gsel * 2 + ks][j] = (_Float16)p[j];
            }
        }
        const float bhn = bhh0[128 + gc];
        bias3 = (f32x4){bhn, bhn, bhn, bhn};
    } else {
#pragma unroll
        for (int gsel = 0; gsel < 3; ++gsel) {
            const int g = gsel * 64 + gc;
#pragma unroll
            for (int ks = 0; ks < 2; ++ks) {
                const float* pa = Wih1 + g * Hn + ks * 32 + q * 8;
                const float* pb = Whh1 + g * Hn + ks * 32 + q * 8;
#pragma unroll
                for (int j = 0; j < 8; ++j) {
                    W[gsel * 2 + ks][j]     = (_Float16)pa[j];
                    W[6 + gsel * 2 + ks][j] = (_Float16)pb[j];
                }
            }
        }
        const float br = bih1[gc] + bhh1[gc];
        const float bz = bih1[64 + gc] + bhh1[64 + gc];
        const float bxn = bih1[128 + gc];
        const float bhn = bhh1[128 + gc];
        bias0 = (f32x4){br, br, br, br};
        bias1 = (f32x4){bz, bz, bz, bz};
        bias2 = (f32x4){bxn, bxn, bxn, bxn};
        bias3 = (f32x4){bhn, bhn, bhn, bhn};
    }

    const int ardr = c * HS + q * 8;        // A-frag read base (+ks*32)
    const int wrow = (q * 4) * HS + gc;     // C-layout write base (+i*HS)

    // Tick t: P makes gx(t+1) (t<Tn-1); L0 makes h0(t) (t<Tn); L1 makes h1(t-1) (t>=1)
    for (int t = 0; t <= Tn; ++t) {
        __syncthreads();
        const int pr = (t & 1) ^ 1, pw = t & 1;
        if (role == 0) {
            if (t < Tn - 1) {
                half8 xf[4];
#pragma unroll
                for (int ks = 0; ks < 4; ++ks)
#pragma unroll
                    for (int i = 0; i < 4; ++i) {
                        xf[ks][i]     = (_Float16)xf32[2 * ks][i];
                        xf[ks][4 + i] = (_Float16)xf32[2 * ks + 1][i];
                    }
                const int tnx = (t + 2 < Tn) ? (t + 2) : (Tn - 1);
#pragma unroll
                for (int ks = 0; ks < 4; ++ks) {
                    xf32[2 * ks]     = *(const f32x4*)(srow + (size_t)tnx * Fn + ks * 32 + q * 8);
                    xf32[2 * ks + 1] = *(const f32x4*)(srow + (size_t)tnx * Fn + ks * 32 + q * 8 + 4);
                }
                f32x4 a0 = bias0, a1 = bias1, a2 = bias2;
#pragma unroll
                for (int ks = 0; ks < 4; ++ks) {
                    a0 = MFMA(xf[ks], W[ks], a0);
                    a1 = MFMA(xf[ks], W[4 + ks], a1);
                    a2 = MFMA(xf[ks], W[8 + ks], a2);
                }
                const int slot = (t + 1) & 1;
                *(f32x4*)&gxring[slot][wv][0][lane][0] = a0;
                *(f32x4*)&gxring[slot][wv][1][lane][0] = a1;
                *(f32x4*)&gxring[slot][wv][2][lane][0] = a2;
            }
        } else if (role == 1) {
            if (t < Tn) {
                f32x4 accr  = *(const f32x4*)&gxring[t & 1][wv][0][lane][0];
                f32x4 accz  = *(const f32x4*)&gxring[t & 1][wv][1][lane][0];
                f32x4 accxn = *(const f32x4*)&gxring[t & 1][wv][2][lane][0];
                const half8 hf0 = *(const half8*)&h0buf[pr][ardr];
                const half8 hf1 = *(const half8*)&h0buf[pr][ardr + 32];
                accr = MFMA(hf0, W[0], accr);
                accr = MFMA(hf1, W[1], accr);
                accz = MFMA(hf0, W[2], accz);
                accz = MFMA(hf1, W[3], accz);
                f32x4 acchn = MFMA(hf0, W[4], bias3);
                acchn = MFMA(hf1, W[5], acchn);
#pragma unroll
                for (int i = 0; i < 4; ++i) {
                    const float rg = sigm(accr[i]);
                    const float zg = sigm(accz[i]);
                    const float ng = tanh_f(accxn[i] + rg * acchn[i]);
                    hreg[i] = ng + zg * (hreg[i] - ng);
                }
#pragma unroll
                for (int i = 0; i < 4; ++i) h0buf[pw][wrow + i * HS] = (_Float16)hreg[i];
            }
        } else {
            if (t >= 1) {
                const half8 xf0 = *(const half8*)&h0buf[pr][ardr];
                const half8 xf1 = *(const half8*)&h0buf[pr][ardr + 32];
                const half8 hf0 = *(const half8*)&h1buf[pw][ardr];
                const half8 hf1 = *(const half8*)&h1buf[pw][ardr + 32];
                f32x4 accr = MFMA(xf0, W[0], bias0);
                accr = MFMA(xf1, W[1], accr);
                f32x4 accz = MFMA(xf0, W[2], bias1);
                accz = MFMA(xf1, W[3], accz);
                f32x4 accxn = MFMA(xf0, W[4], bias2);
                accxn = MFMA(xf1, W[5], accxn);
                accr = MFMA(hf0, W[6], accr);
                accr = MFMA(hf1, W[7], accr);
                accz = MFMA(hf0, W[8], accz);
                accz = MFMA(hf1, W[9], accz);
                f32x4 acchn = MFMA(hf0, W[10], bias3);
                acchn = MFMA(hf1, W[11], acchn);
#pragma unroll
                for (int i = 0; i < 4; ++i) {
                    const float rg = sigm(accr[i]);
                    const float zg = sigm(accz[i]);
                    const float ng = tanh_f(accxn[i] + rg * acchn[i]);
                    hreg[i] = ng + zg * (hreg[i] - ng);
                }
#pragma unroll
                for (int i = 0; i < 4; ++i) h1buf[pr][wrow + i * HS] = (_Float16)hreg[i];
            }
        }
    }

    // epilogue: relu(h1_final) @ fc3_w.T + fc3_b
    if (role == 2) {
#pragma unroll
        for (int i = 0; i < 4; ++i) fbuf[(q * 4 + i) * 64 + gc] = fmaxf(hreg[i], 0.0f);
    }
    __syncthreads();
    for (int idx = tid; idx < 16 * An; idx += 768) {
        const int row = idx / An, a = idx - row * An;
        float acc = fcb[a];
#pragma unroll 16
        for (int k = 0; k < Hn; ++k) acc += fbuf[row * 64 + k] * fcw[a * Hn + k];
        out[(size_t)(r0 + row) * An + a] = acc;
    }
}

extern "C" void kernel_launch(void* const* d_in, const int* in_sizes, int n_in,
                              void* d_out, int out_size, void* d_ws, size_t ws_size,
                              hipStream_t stream) {
    const float* state = (const float*)d_in[0];
    const float* Wih0  = (const float*)d_in[1];
    const float* Whh0  = (const float*)d_in[2];
    const float* bih0  = (const float*)d_in[3];
    const float* bhh0  = (const float*)d_in[4];
    const float* Wih1  = (const float*)d_in[5];
    const float* Whh1  = (const float*)d_in[6];
    const float* bih1  = (const float*)d_in[7];
    const float* bhh1  = (const float*)d_in[8];
    const float* fcw   = (const float*)d_in[9];
    const float* fcb   = (const float*)d_in[10];
    float* out = (float*)d_out;

    gru_fused<<<64, 768, 0, stream>>>(state, Wih0, Whh0, bih0, bhh0,
                                      Wih1, Whh1, bih1, bhh1, fcw, fcb, out);
}